// Round 1
// 320.047 us; speedup vs baseline: 1.0187x; 1.0187x over previous
//
#include <hip/hip_runtime.h>

#define N_NODES 100000
#define DEG 16
#define DIM 128
#define NTILES 1563          // ceil(100000/64)
#define T8 196               // ceil(NTILES/8)
#define DGRID (T8 * 4 * 8)   // 6272 (some inert)
#define LSTR 136             // LDS row stride in shorts (16B-aligned, conflict-light)

typedef short bf16x8 __attribute__((ext_vector_type(8)));
typedef float f32x4 __attribute__((ext_vector_type(4)));

__device__ __forceinline__ unsigned short f2bf(float f) {
    unsigned int u = __builtin_bit_cast(unsigned int, f);
    u = (u + 0x7fffu + ((u >> 16) & 1u)) >> 16;
    return (unsigned short)u;
}
__device__ __forceinline__ float bf2f(unsigned short h) {
    unsigned int u = ((unsigned int)h) << 16;
    return __builtin_bit_cast(float, u);
}
__device__ __forceinline__ bf16x8 pack_bf16x8(float4 lo, float4 hi) {
    bf16x8 f;
    f[0] = (short)f2bf(lo.x); f[1] = (short)f2bf(lo.y);
    f[2] = (short)f2bf(lo.z); f[3] = (short)f2bf(lo.w);
    f[4] = (short)f2bf(hi.x); f[5] = (short)f2bf(hi.y);
    f[6] = (short)f2bf(hi.z); f[7] = (short)f2bf(hi.w);
    return f;
}

// ---------------------------------------------------------------------------
// prep: cast W_W1|W_U1 -> Wc1 (256x128 bf16), W_W2|W_U2 -> Wc2
// ---------------------------------------------------------------------------
__global__ __launch_bounds__(256) void prep_w(
    const float* __restrict__ W_W1, const float* __restrict__ W_U1,
    const float* __restrict__ W_W2, const float* __restrict__ W_U2,
    unsigned short* __restrict__ Wc1, unsigned short* __restrict__ Wc2)
{
    int idx = blockIdx.x * 256 + threadIdx.x;      // 0..65535
    int half = idx & 32767;
    const float* src = (idx < 32768)
        ? (half < 16384 ? W_W1 + half : W_U1 + half - 16384)
        : (half < 16384 ? W_W2 + half : W_U2 + half - 16384);
    unsigned short* dst = (idx < 32768) ? Wc1 + half : Wc2 + half;
    *dst = f2bf(*src);
}

// ---------------------------------------------------------------------------
// dense1: z1 = attr @ W_W1^T, zi1 = attr @ W_U1^T (bf16) + score partials.
// Block = 64 nodes x 64 output cols. 1-D grid, XCD-swizzled so the 4
// col-blocks of one tile land on the SAME XCD (h fetched once per tile).
// ---------------------------------------------------------------------------
__global__ __launch_bounds__(256, 4) void dense_tile(
    const float* __restrict__ hsrc,          // N x 128 f32 (attr)
    const unsigned short* __restrict__ Wc,   // 256 x 128 bf16 (W_W1|W_U1)
    const float* __restrict__ W_a,           // 257 f32
    unsigned short* __restrict__ z,          // N x 128 bf16
    unsigned short* __restrict__ zi,         // N x 128 bf16
    float* __restrict__ s_src0, float* __restrict__ s_src1,
    float* __restrict__ s_dst0, float* __restrict__ s_dst1)
{
    __shared__ unsigned short Wt[64 * LSTR];
    __shared__ unsigned short Ht[64 * LSTR];

    // swizzle: same-XCD consecutive blocks = 4 col-blocks of one tile
    const int bid = blockIdx.x;
    const int xcd = bid & 7;
    const int q = bid >> 3;
    const int cb = q & 3;                    // col-block 0..3
    const int tile = (q >> 2) * 8 + xcd;
    if (tile >= NTILES) return;
    const int nodebase = tile * 64;
    const int t = threadIdx.x;

    // ---- stage W slice (bf16, plain copies) ----
    {
        int r = t >> 2, c0 = (t & 3) * 32;
        const unsigned short* src = Wc + (size_t)(cb * 64 + r) * DIM + c0;
        unsigned short* dst = Wt + r * LSTR + c0;
#pragma unroll
        for (int i = 0; i < 4; i++)
            *(uint4*)(dst + i * 8) = *(const uint4*)(src + i * 8);
    }
    // ---- stage h tile: 64 nodes x 128 f32 -> bf16 ----
    {
        int r = t >> 2, c0 = (t & 3) * 32;
        int node = nodebase + r;
        unsigned short* dst = Ht + r * LSTR + c0;
        float4 v[8];
#pragma unroll
        for (int i = 0; i < 8; i++) v[i] = make_float4(0.f, 0.f, 0.f, 0.f);
        if (node < N_NODES) {
            const float* src = hsrc + (size_t)node * DIM + c0;
#pragma unroll
            for (int i = 0; i < 8; i++) v[i] = *(const float4*)(src + i * 4);
        }
#pragma unroll
        for (int i = 0; i < 4; i++)
            *(bf16x8*)(dst + i * 8) = pack_bf16x8(v[2 * i], v[2 * i + 1]);
    }
    __syncthreads();

    const int wave = t >> 6;
    const int lane = t & 63;
    const int n16 = lane & 15;
    const int quad = lane >> 4;
    const int node = nodebase + wave * 16 + n16;

    bf16x8 hfrag[4];
    const unsigned short* hrow = Ht + (wave * 16 + n16) * LSTR + quad * 8;
#pragma unroll
    for (int ks = 0; ks < 4; ks++)
        hfrag[ks] = *(const bf16x8*)(hrow + ks * 32);

    f32x4 acc[4];
#pragma unroll
    for (int ct = 0; ct < 4; ct++) {
        const unsigned short* wrow = Wt + (ct * 16 + n16) * LSTR + quad * 8;
        f32x4 a = {0.f, 0.f, 0.f, 0.f};
#pragma unroll
        for (int ks = 0; ks < 4; ks++)
            a = __builtin_amdgcn_mfma_f32_16x16x32_bf16(
                    *(const bf16x8*)(wrow + ks * 32), hfrag[ks], a, 0, 0, 0);
        acc[ct] = a;
    }

    if (node < N_NODES) {
        unsigned short* zout = (cb < 2 ? z : zi);
        unsigned short* orow = zout + (size_t)node * DIM + (cb & 1) * 64 + quad * 4;
#pragma unroll
        for (int ct = 0; ct < 4; ct++) {
            uint2 pk;
            pk.x = (unsigned int)f2bf(acc[ct][0]) | ((unsigned int)f2bf(acc[ct][1]) << 16);
            pk.y = (unsigned int)f2bf(acc[ct][2]) | ((unsigned int)f2bf(acc[ct][3]) << 16);
            *(uint2*)(orow + ct * 16) = pk;
        }
    }

    if (cb < 2) {
        float ps = 0.f, pd = 0.f;
#pragma unroll
        for (int ct = 0; ct < 4; ct++) {
            float4 as = *(const float4*)(W_a + cb * 64 + ct * 16 + quad * 4);
            float4 ad = *(const float4*)(W_a + DIM + cb * 64 + ct * 16 + quad * 4);
            ps += acc[ct][0] * as.x + acc[ct][1] * as.y
                + acc[ct][2] * as.z + acc[ct][3] * as.w;
            pd += acc[ct][0] * ad.x + acc[ct][1] * ad.y
                + acc[ct][2] * ad.z + acc[ct][3] * ad.w;
        }
        ps += __shfl_xor(ps, 16); ps += __shfl_xor(ps, 32);
        pd += __shfl_xor(pd, 16); pd += __shfl_xor(pd, 32);
        if (lane < 16 && node < N_NODES) {
            (cb == 0 ? s_src0 : s_src1)[node] = ps;
            (cb == 0 ? s_dst0 : s_dst1)[node] = pd;
        }
    }
}

// ---------------------------------------------------------------------------
// aggr_dense: 16 nodes/block. Layer-1 softmax-aggregate (h1 -> LDS only),
// then layer-2 dense (z2/zi2 = h1 @ W2^T) + layer-2 score partials.
//
// v6 restructure: softmax alpha/src exchange is done with intra-wave __shfl
// (phase-1 lane (nl,j) and phase-2 lane (nl,colslice j) are the SAME 16-lane
// group), so the two pre-gather barriers are gone. All 17 gather loads are
// issued up front (sched_barrier pins the issue), and the softmax scalar
// loads + VALU run while they are in flight. Single barrier remains before
// the fused layer-2 MFMA (Hl staging is cross-wave).
// ---------------------------------------------------------------------------
__global__ __launch_bounds__(256, 3) void aggr_dense(
    const unsigned short* __restrict__ z,    // z1
    const unsigned short* __restrict__ zi,   // zi1
    const float* __restrict__ s_src0, const float* __restrict__ s_src1,
    const float* __restrict__ s_dst0, const float* __restrict__ s_dst1,
    const float* __restrict__ edge_d,
    const int* __restrict__ edge_src,
    const float* __restrict__ W_V,           // W_V1 (1 float)
    const float* __restrict__ W_a,           // W_a1 (a_t = [256])
    const unsigned short* __restrict__ Wc2,  // 256 x 128 bf16 (W_W2|W_U2)
    const float* __restrict__ W_a2,          // 257 f32 (layer-2 scores)
    unsigned short* __restrict__ z2,
    unsigned short* __restrict__ zi2,
    float* __restrict__ t_src0, float* __restrict__ t_src1,
    float* __restrict__ t_dst0, float* __restrict__ t_dst1)
{
    __shared__ unsigned short Hl[16 * LSTR];

    const int t = threadIdx.x;
    const int base = blockIdx.x * 16;
    const int nl = t >> 4;          // node within block 0..15
    const int j  = t & 15;          // edge index == col-slice index
    const int nodej = base + nl;
    const int lane = t & 63;
    const int gb = lane & 48;       // 16-lane group base within wave

    const int e = nodej * DEG + j;

    // own-edge metadata (coalesced)
    int   s  = edge_src[e];
    float ed = edge_d[e];

    // score loads: 4 scattered dwords, oldest in the vmcnt queue so the
    // softmax VALU below only waits on these, not on the gathers.
    float v_ss0 = s_src0[s];
    float v_ss1 = s_src1[s];
    float v_sd0 = s_dst0[nodej];
    float v_sd1 = s_dst1[nodej];

    // broadcast the 16 srcs of this node within the group, issue ALL gathers
    const int c8 = j * 8;
    uint4 raw[DEG];
#pragma unroll
    for (int jj = 0; jj < DEG; jj++) {
        int sj = __shfl(s, gb | jj);
        raw[jj] = *(const uint4*)(z + (size_t)sj * DIM + c8);
    }
    uint4 zr = *(const uint4*)(zi + (size_t)nodej * DIM + c8);
    __builtin_amdgcn_sched_barrier(0);   // pin: all gathers issued before consume

    // ---- softmax while gathers are in flight ----
    float coef = W_V[0] * W_a[2 * DIM];
    float x = (v_ss0 + v_ss1) + (v_sd0 + v_sd1) + ed * coef;
    x = x > 0.f ? x : 0.01f * x;
    float m = x;
    m = fmaxf(m, __shfl_xor(m, 1));
    m = fmaxf(m, __shfl_xor(m, 2));
    m = fmaxf(m, __shfl_xor(m, 4));
    m = fmaxf(m, __shfl_xor(m, 8));
    float ex = __expf(x - m);
    float d = ex;
    d += __shfl_xor(d, 1); d += __shfl_xor(d, 2);
    d += __shfl_xor(d, 4); d += __shfl_xor(d, 8);
    float aj = ex / d;               // this lane's own alpha (edge j)

    // ---- consume gathers ----
    float acc8[8] = {};
#pragma unroll
    for (int jj = 0; jj < DEG; jj++) {
        float a = __shfl(aj, gb | jj);
        acc8[0] += a * bf2f((unsigned short)raw[jj].x);
        acc8[1] += a * bf2f((unsigned short)(raw[jj].x >> 16));
        acc8[2] += a * bf2f((unsigned short)raw[jj].y);
        acc8[3] += a * bf2f((unsigned short)(raw[jj].y >> 16));
        acc8[4] += a * bf2f((unsigned short)raw[jj].z);
        acc8[5] += a * bf2f((unsigned short)(raw[jj].z >> 16));
        acc8[6] += a * bf2f((unsigned short)raw[jj].w);
        acc8[7] += a * bf2f((unsigned short)(raw[jj].w >> 16));
    }

    float v[8];
    v[0] = fmaxf(bf2f((unsigned short)zr.x) + acc8[0], 0.f);
    v[1] = fmaxf(bf2f((unsigned short)(zr.x >> 16)) + acc8[1], 0.f);
    v[2] = fmaxf(bf2f((unsigned short)zr.y) + acc8[2], 0.f);
    v[3] = fmaxf(bf2f((unsigned short)(zr.y >> 16)) + acc8[3], 0.f);
    v[4] = fmaxf(bf2f((unsigned short)zr.z) + acc8[4], 0.f);
    v[5] = fmaxf(bf2f((unsigned short)(zr.z >> 16)) + acc8[5], 0.f);
    v[6] = fmaxf(bf2f((unsigned short)zr.w) + acc8[6], 0.f);
    v[7] = fmaxf(bf2f((unsigned short)(zr.w >> 16)) + acc8[7], 0.f);

    {
        uint4 pk;
        pk.x = (unsigned int)f2bf(v[0]) | ((unsigned int)f2bf(v[1]) << 16);
        pk.y = (unsigned int)f2bf(v[2]) | ((unsigned int)f2bf(v[3]) << 16);
        pk.z = (unsigned int)f2bf(v[4]) | ((unsigned int)f2bf(v[5]) << 16);
        pk.w = (unsigned int)f2bf(v[6]) | ((unsigned int)f2bf(v[7]) << 16);
        *(uint4*)(Hl + nl * LSTR + c8) = pk;
    }
    __syncthreads();

    // ---- layer-2 dense for these 16 nodes ----
    const int wave = t >> 6;
    const int n16 = lane & 15;
    const int quad = lane >> 4;
    const int node = base + n16;

    bf16x8 hfrag[4];
    const unsigned short* hrow = Hl + n16 * LSTR + quad * 8;
#pragma unroll
    for (int ks = 0; ks < 4; ks++)
        hfrag[ks] = *(const bf16x8*)(hrow + ks * 32);

    f32x4 acc[4];
#pragma unroll
    for (int ct = 0; ct < 4; ct++) {
        const unsigned short* wrow = Wc2 + (size_t)(wave * 64 + ct * 16 + n16) * DIM + quad * 8;
        f32x4 a = {0.f, 0.f, 0.f, 0.f};
#pragma unroll
        for (int ks = 0; ks < 4; ks++)
            a = __builtin_amdgcn_mfma_f32_16x16x32_bf16(
                    *(const bf16x8*)(wrow + ks * 32), hfrag[ks], a, 0, 0, 0);
        acc[ct] = a;
    }

    {
        unsigned short* zout = (wave < 2 ? z2 : zi2);
        unsigned short* orow = zout + (size_t)node * DIM + (wave & 1) * 64 + quad * 4;
#pragma unroll
        for (int ct = 0; ct < 4; ct++) {
            uint2 pk;
            pk.x = (unsigned int)f2bf(acc[ct][0]) | ((unsigned int)f2bf(acc[ct][1]) << 16);
            pk.y = (unsigned int)f2bf(acc[ct][2]) | ((unsigned int)f2bf(acc[ct][3]) << 16);
            *(uint2*)(orow + ct * 16) = pk;
        }
    }

    if (wave < 2) {
        float ps = 0.f, pd = 0.f;
#pragma unroll
        for (int ct = 0; ct < 4; ct++) {
            float4 as = *(const float4*)(W_a2 + wave * 64 + ct * 16 + quad * 4);
            float4 ad = *(const float4*)(W_a2 + DIM + wave * 64 + ct * 16 + quad * 4);
            ps += acc[ct][0] * as.x + acc[ct][1] * as.y
                + acc[ct][2] * as.z + acc[ct][3] * as.w;
            pd += acc[ct][0] * ad.x + acc[ct][1] * ad.y
                + acc[ct][2] * ad.z + acc[ct][3] * ad.w;
        }
        ps += __shfl_xor(ps, 16); ps += __shfl_xor(ps, 32);
        pd += __shfl_xor(pd, 16); pd += __shfl_xor(pd, 32);
        if (lane < 16) {
            (wave == 0 ? t_src0 : t_src1)[node] = ps;
            (wave == 0 ? t_dst0 : t_dst1)[node] = pd;
        }
    }
}

// ---------------------------------------------------------------------------
// aggr_final: same restructure — barrier-free, zero LDS, all-shfl softmax,
// gathers issued up front. Writes f32 output.
// ---------------------------------------------------------------------------
__global__ __launch_bounds__(256, 3) void aggr_final(
    const unsigned short* __restrict__ z,    // z2
    const unsigned short* __restrict__ zi,   // zi2
    const float* __restrict__ s_src0, const float* __restrict__ s_src1,
    const float* __restrict__ s_dst0, const float* __restrict__ s_dst1,
    const float* __restrict__ edge_d,
    const int* __restrict__ edge_src,
    const float* __restrict__ W_V,           // W_V2
    const float* __restrict__ W_a,           // W_a2
    float* __restrict__ out_f32)
{
    const int t = threadIdx.x;
    const int base = blockIdx.x * 16;
    const int nl = t >> 4;
    const int j  = t & 15;
    const int node = base + nl;
    const int lane = t & 63;
    const int gb = lane & 48;

    const int e = node * DEG + j;

    int   s  = edge_src[e];
    float ed = edge_d[e];

    float v_ss0 = s_src0[s];
    float v_ss1 = s_src1[s];
    float v_sd0 = s_dst0[node];
    float v_sd1 = s_dst1[node];

    const int c8 = j * 8;
    uint4 raw[DEG];
#pragma unroll
    for (int jj = 0; jj < DEG; jj++) {
        int sj = __shfl(s, gb | jj);
        raw[jj] = *(const uint4*)(z + (size_t)sj * DIM + c8);
    }
    uint4 zr = *(const uint4*)(zi + (size_t)node * DIM + c8);
    __builtin_amdgcn_sched_barrier(0);

    float coef = W_V[0] * W_a[2 * DIM];
    float x = (v_ss0 + v_ss1) + (v_sd0 + v_sd1) + ed * coef;
    x = x > 0.f ? x : 0.01f * x;
    float m = x;
    m = fmaxf(m, __shfl_xor(m, 1));
    m = fmaxf(m, __shfl_xor(m, 2));
    m = fmaxf(m, __shfl_xor(m, 4));
    m = fmaxf(m, __shfl_xor(m, 8));
    float ex = __expf(x - m);
    float d = ex;
    d += __shfl_xor(d, 1); d += __shfl_xor(d, 2);
    d += __shfl_xor(d, 4); d += __shfl_xor(d, 8);
    float aj = ex / d;

    float acc[8] = {};
#pragma unroll
    for (int jj = 0; jj < DEG; jj++) {
        float a = __shfl(aj, gb | jj);
        acc[0] += a * bf2f((unsigned short)raw[jj].x);
        acc[1] += a * bf2f((unsigned short)(raw[jj].x >> 16));
        acc[2] += a * bf2f((unsigned short)raw[jj].y);
        acc[3] += a * bf2f((unsigned short)(raw[jj].y >> 16));
        acc[4] += a * bf2f((unsigned short)raw[jj].z);
        acc[5] += a * bf2f((unsigned short)(raw[jj].z >> 16));
        acc[6] += a * bf2f((unsigned short)raw[jj].w);
        acc[7] += a * bf2f((unsigned short)(raw[jj].w >> 16));
    }

    float* op = out_f32 + (size_t)node * DIM + c8;
    *(float4*)op = make_float4(
        fmaxf(bf2f((unsigned short)zr.x) + acc[0], 0.f),
        fmaxf(bf2f((unsigned short)(zr.x >> 16)) + acc[1], 0.f),
        fmaxf(bf2f((unsigned short)zr.y) + acc[2], 0.f),
        fmaxf(bf2f((unsigned short)(zr.y >> 16)) + acc[3], 0.f));
    *(float4*)(op + 4) = make_float4(
        fmaxf(bf2f((unsigned short)zr.z) + acc[4], 0.f),
        fmaxf(bf2f((unsigned short)(zr.z >> 16)) + acc[5], 0.f),
        fmaxf(bf2f((unsigned short)zr.w) + acc[6], 0.f),
        fmaxf(bf2f((unsigned short)(zr.w >> 16)) + acc[7], 0.f));
}

// ---------------------------------------------------------------------------
extern "C" void kernel_launch(void* const* d_in, const int* in_sizes, int n_in,
                              void* d_out, int out_size, void* d_ws, size_t ws_size,
                              hipStream_t stream) {
    const float* attr     = (const float*)d_in[0];
    const float* edge_d   = (const float*)d_in[1];
    const float* W_V1     = (const float*)d_in[2];
    const float* W_W1     = (const float*)d_in[3];
    const float* W_U1     = (const float*)d_in[4];
    const float* W_a1     = (const float*)d_in[5];
    const float* W_V2     = (const float*)d_in[6];
    const float* W_W2     = (const float*)d_in[7];
    const float* W_U2     = (const float*)d_in[8];
    const float* W_a2     = (const float*)d_in[9];
    const int*   edge_src = (const int*)d_in[10];

    float* out = (float*)d_out;

    char* ws = (char*)d_ws;
    unsigned short* z1  = (unsigned short*)ws;                         // 25.6 MB
    unsigned short* zi1 = (unsigned short*)(ws + 26u * 1024 * 1024);
    unsigned short* z2  = (unsigned short*)(ws + 52u * 1024 * 1024);
    unsigned short* zi2 = (unsigned short*)(ws + 78u * 1024 * 1024);
    unsigned short* Wc1 = (unsigned short*)(ws + 104u * 1024 * 1024);  // 64 KB
    unsigned short* Wc2 = (unsigned short*)(ws + 105u * 1024 * 1024);  // 64 KB
    float* s_src0       = (float*)(ws + 106u * 1024 * 1024);
    float* s_src1       = (float*)(ws + 107u * 1024 * 1024);
    float* s_dst0       = (float*)(ws + 108u * 1024 * 1024);
    float* s_dst1       = (float*)(ws + 109u * 1024 * 1024);
    float* t_src0       = (float*)(ws + 110u * 1024 * 1024);
    float* t_src1       = (float*)(ws + 111u * 1024 * 1024);
    float* t_dst0       = (float*)(ws + 112u * 1024 * 1024);
    float* t_dst1       = (float*)(ws + 113u * 1024 * 1024);

    prep_w<<<256, 256, 0, stream>>>(W_W1, W_U1, W_W2, W_U2, Wc1, Wc2);

    dense_tile<<<DGRID, 256, 0, stream>>>(attr, Wc1, W_a1, z1, zi1,
                                          s_src0, s_src1, s_dst0, s_dst1);

    aggr_dense<<<6250, 256, 0, stream>>>(z1, zi1, s_src0, s_src1, s_dst0, s_dst1,
                                         edge_d, edge_src, W_V1, W_a1,
                                         Wc2, W_a2, z2, zi2,
                                         t_src0, t_src1, t_dst0, t_dst1);

    aggr_final<<<6250, 256, 0, stream>>>(z2, zi2, t_src0, t_src1, t_dst0, t_dst1,
                                         edge_d, edge_src, W_V2, W_a2, out);
}